// Round 8
// baseline (364.981 us; speedup 1.0000x reference)
//
#include <hip/hip_runtime.h>
#include <stdint.h>

// MultiHeadAttention: B=2, S=2048, D=2048, H=16, Dh=128, fp32 in/out.
// R13: mm_core BK 64->32, LDS 72 KiB triple-buffer -> 2 blocks/CU
//      (4 waves/SIMD, cross-block overlap a la m97/m114; R12 was 1 block/CU,
//      2 waves/SIMD, OccupancyPercent ~20 and ~850 cyc/tile of un-overlapped
//      read/MFMA alternation). Read:MFMA ratio unchanged; vmcnt(3) ledger
//      (stage t+2 during t, retire t+1); BK=32 bank swizzle j=quad^((r>>1)&3)
//      (8 slots/8 rows = 2-way = free). launch_bounds(512,4) caps VGPR 128.
//      attn / conv_all / epilogues unchanged from R12 (session best 343us).

#define SEQ 2048
#define HD 128
#define DMODEL 2048

typedef __bf16 bf16x8 __attribute__((ext_vector_type(8)));
typedef float f32x4 __attribute__((ext_vector_type(4)));
typedef unsigned short u16;
typedef unsigned int u32;

typedef bf16x8 __attribute__((may_alias)) bf16x8_a;
typedef uint2 __attribute__((may_alias)) uint2_a;
typedef uint4 __attribute__((may_alias)) uint4_a;

__device__ __forceinline__ u16 f2bf(float f) {
  unsigned int u = __float_as_uint(f);
  u += 0x7fff + ((u >> 16) & 1);   // RNE; inputs are finite normals
  return (u16)(u >> 16);
}

typedef __attribute__((address_space(1))) void* gas_t;
typedef __attribute__((address_space(3))) void* las_t;
// async global->LDS, 16B/lane. LDS dest must be uniform base + lane*16.
__device__ __forceinline__ void load_lds16(const void* g, void* l) {
  __builtin_amdgcn_global_load_lds((gas_t)(uintptr_t)g,
                                   (las_t)(uint32_t)(uintptr_t)l, 16, 0, 0);
}

// ---------------- fp32 -> bf16 convert (all 5 tensors, one launch) ---------
__global__ void conv_all(const float* __restrict__ x,
                         const float* __restrict__ wq,
                         const float* __restrict__ wk,
                         const float* __restrict__ wv,
                         const float* __restrict__ wo,
                         u16* __restrict__ xb, u16* __restrict__ wqkv,
                         u16* __restrict__ wob) {
  int i = blockIdx.x * 256 + threadIdx.x;  // float4 index
  const float* src;
  u16* dst;
  int off;
  if (i < 2097152) { src = x; dst = xb; off = i; }
  else if (i < 3145728) { src = wq; dst = wqkv; off = i - 2097152; }
  else if (i < 4194304) { src = wk; dst = wqkv + 4194304; off = i - 3145728; }
  else if (i < 5242880) { src = wv; dst = wqkv + 8388608; off = i - 4194304; }
  else { src = wo; dst = wob; off = i - 5242880; }
  float4 v = ((const float4*)src)[off];
  ushort4 o;
  o.x = f2bf(v.x); o.y = f2bf(v.y); o.z = f2bf(v.z); o.w = f2bf(v.w);
  ((ushort4*)dst)[off] = o;
}

// ========= 256x128-tile, BK=32, TRIPLE-buffered GEMM core (R13) ============
// 8 waves 4M x 2N (wave tile 64x64, acc[4][4]); 64 K-tiles of 32.
// LDS 72 KiB: A[3][256x32] (48 KB) + B[3][128x32] (24 KB) -> 2 blocks/CU.
// Per tile t (CUR = t%3 via 3-step unroll), ONE barrier:
//   { ds_read A+B frags (8 b128/wave); stage(t+2) A (2) + B (1);
//     16 MFMA; vmcnt(3); s_barrier; }
// vmcnt(3): outstanding = stage(t+1) 3 + stage(t+2) 3 -> retires stage(t+1)
// (issued one full tile ago). Deadness: buf (t+2)%3 last ds_read at t-1,
// all reads retired before each wave's own MFMAs -> dead at the barrier.
// Swizzle: global source atom a_src = (idx&3) ^ ((row>>1)&3), LDS linear;
// read applies the same XOR -> 8 distinct 16B slots per 8 rows (2-way, free).

#define BARR asm volatile("s_barrier" ::: "memory")
#define VMW3 asm volatile("s_waitcnt vmcnt(3)" ::: "memory")
#define VMW8 asm volatile("s_waitcnt vmcnt(8)" ::: "memory")
#define VMW0 asm volatile("s_waitcnt vmcnt(0)" ::: "memory")

#define STGA32(D, KOFF) do {                                                \
    const u16* ga_ = Ag + (KOFF);                                           \
    u16* la_ = S + (D) * 8192;                                              \
    load_lds16(ga_ + offA0, la_ + tid * 8);                                 \
    load_lds16(ga_ + offA1, la_ + (tid + 512) * 8);                         \
  } while (0)

#define STGB32(D, KOFF) do {                                                \
    const u16* gb_ = Bg + (KOFF);                                           \
    u16* lb_ = S + 24576 + (D) * 4096;                                      \
    load_lds16(gb_ + offA0, lb_ + tid * 8);                                 \
  } while (0)

#define LDAB32(D) do {                                                      \
    const u16* ab_ = S + (D) * 8192;                                        \
    const u16* bb_ = S + 24576 + (D) * 4096;                                \
    _Pragma("unroll") for (int mt_ = 0; mt_ < 4; ++mt_) {                   \
      int rA_ = wm * 64 + mt_ * 16 + l15;                                   \
      af[mt_] = *(const bf16x8_a*)(ab_ + rA_ * 32 +                         \
                                   ((quad ^ ((rA_ >> 1) & 3)) * 8));        \
    }                                                                       \
    _Pragma("unroll") for (int nt_ = 0; nt_ < 4; ++nt_) {                   \
      int rB_ = wn * 64 + nt_ * 16 + l15;                                   \
      bfr[nt_] = *(const bf16x8_a*)(bb_ + rB_ * 32 +                        \
                                    ((quad ^ ((rB_ >> 1) & 3)) * 8));       \
    } } while (0)

#define MM32() do {                                                         \
    __builtin_amdgcn_s_setprio(1);                                          \
    _Pragma("unroll") for (int mt_ = 0; mt_ < 4; ++mt_)                     \
      _Pragma("unroll") for (int nt_ = 0; nt_ < 4; ++nt_) {                 \
        if (VM)                                                             \
          acc[mt_][nt_] = __builtin_amdgcn_mfma_f32_16x16x32_bf16(          \
              bfr[nt_], af[mt_], acc[mt_][nt_], 0, 0, 0);                   \
        else                                                                \
          acc[mt_][nt_] = __builtin_amdgcn_mfma_f32_16x16x32_bf16(          \
              af[mt_], bfr[nt_], acc[mt_][nt_], 0, 0, 0);                   \
      }                                                                     \
    __builtin_amdgcn_s_setprio(0);                                          \
  } while (0)

// one steady-state K-tile; CUR/NX2 compile-time via 3-step unroll
#define STEP32(T, CUR, NX2) do {                                            \
    LDAB32(CUR);                                                            \
    STGA32(NX2, ((T) + 2) * 32);                                            \
    STGB32(NX2, ((T) + 2) * 32);                                            \
    MM32();                                                                 \
    VMW3; BARR;                                                             \
  } while (0)

template <bool VM>
__device__ __forceinline__ void mm_core(const u16* __restrict__ Ag,
                                        const u16* __restrict__ Bg,
                                        u16* __restrict__ S, int tid,
                                        f32x4 acc[4][4]) {
  const int lane = tid & 63;
  const int wave = tid >> 6;
  const int quad = lane >> 4;
  const int l15 = lane & 15;
  const int wm = wave >> 1;
  const int wn = wave & 1;

  // staging source offsets (u16 elems): atom idx -> row idx>>2 (K=2048
  // stride), src atom = (idx&3)^((row>>1)&3); LDS dest linear.
  u32 offA0, offA1;
  {
    int r = tid >> 2;
    offA0 = (u32)r * 2048u + (u32)((((tid & 3) ^ ((r >> 1) & 3)) * 8));
  }
  {
    int i1 = tid + 512;
    int r = i1 >> 2;
    offA1 = (u32)r * 2048u + (u32)((((i1 & 3) ^ ((r >> 1) & 3)) * 8));
  }

  bf16x8 af[4], bfr[4];

  // prologue: tiles 0 and 1 (A+B each); retire tile0, leave tile1 in flight
  STGA32(0, 0);
  STGB32(0, 0);
  STGA32(1, 32);
  STGB32(1, 32);
  VMW3;             // tile0's 3 loads retired; tile1's 3 in flight
  BARR;

  // t = 0..59 in groups of 3 (stages through tile 61)
#pragma unroll 1
  for (int tt = 0; tt < 60; tt += 3) {
    STEP32(tt,     0, 2);
    STEP32(tt + 1, 1, 0);
    STEP32(tt + 2, 2, 1);
  }

  // t = 60 (CUR=0): stage 62 -> buf2
  LDAB32(0);
  STGA32(2, 62 * 32);
  STGB32(2, 62 * 32);
  MM32();
  VMW3; BARR;       // retires stage(61)
  // t = 61 (CUR=1): stage 63 -> buf0 (buf0 last read t=60, dead)
  LDAB32(1);
  STGA32(0, 63 * 32);
  STGB32(0, 63 * 32);
  MM32();
  VMW3; BARR;       // retires stage(62)
  // t = 62 (CUR=2): drain stage(63)
  LDAB32(2);
  MM32();
  VMW0; BARR;
  // t = 63 (CUR=0)
  LDAB32(0);
  MM32();
  BARR;             // all reads done before epilogue reuses S
}

// grid (48, 16), 512 threads. bx<16: Q RoPE; 16-31: K RoPE; 32-47: V^T.
__global__ __launch_bounds__(512, 4)
void gemm_qkv(const u16* __restrict__ A, const u16* __restrict__ Bm,
              u16* __restrict__ qkv, u16* __restrict__ vt) {
  __shared__ __align__(16) u16 S[36864];  // 72 KiB: A[3][8192]+B[3][4096]

  const int tid = threadIdx.x;
  // XCD-aware bijective swizzle, col-major logical order: each XCD owns 6
  // consecutive B-panels (weights resident in its L2); A panels hit L3.
  int hwid = blockIdx.y * 48 + blockIdx.x;
  int logical = (hwid & 7) * 96 + (hwid >> 3);
  const int bx = logical >> 4;       // 0..47 (N tile, 128 cols = 1 head)
  const int by = logical & 15;       // 0..15 (M tile, 256 rows)
  const int row0 = by * 256;
  const int col0 = bx * 128;
  const bool vmode = bx >= 32;

  const u16* Ag = A + (size_t)row0 * 2048;
  const u16* Bg = Bm + (size_t)col0 * 2048;

  f32x4 acc[4][4] = {};
  if (vmode) mm_core<true>(Ag, Bg, S, tid, acc);
  else       mm_core<false>(Ag, Bg, S, tid, acc);

  const int lane = tid & 63;
  const int wave = tid >> 6;
  const int quad = lane >> 4;
  const int l15 = lane & 15;
  const int wm = wave >> 1;
  const int wn = wave & 1;

  const int which = bx >> 4;              // 0=q 1=k 2=v
  const int h = bx & 15;
  const int brow = row0 >> 11;
  const int sbase = row0 & 2047;
  const float qs = (which == 0) ? 0.12751744f : 1.0f;  // log2e/sqrt(128)

  // acc -> bf16 tile in S, atom-XOR swizzled (32 KiB <= 72 KiB)
#pragma unroll
  for (int mt = 0; mt < 4; ++mt)
#pragma unroll
    for (int nt = 0; nt < 4; ++nt)
#pragma unroll
      for (int r = 0; r < 4; ++r) {
        int el;
        if (vmode) {  // C^T tile [d=128][s=256], 32 atoms/row
          int dd = wn * 64 + nt * 16 + quad * 4 + r;
          int ss = wm * 64 + mt * 16 + l15;
          el = dd * 256 + (((ss >> 3) ^ (dd & 31)) * 8) + (ss & 7);
        } else {      // tile [s=256][d=128], 16 atoms/row
          int ss = wm * 64 + mt * 16 + quad * 4 + r;
          int dd = wn * 64 + nt * 16 + l15;
          el = ss * 128 + (((dd >> 3) ^ (ss & 15)) * 8) + (dd & 7);
        }
        S[el] = f2bf(acc[mt][nt][r] * qs);
      }
  __syncthreads();

  if (!vmode) {
    const int a = lane & 7;     // d-atom 0..7 (pairs with a+8)
    const int sg = lane >> 3;   // row-in-group
    const float c1 = 0.2076205059304601f;   // log2(10000)/64
    const float c2 = 2.6514961294723187f;   // log2(2*pi)
#pragma unroll
    for (int pass = 0; pass < 4; ++pass) {
      int s_l = pass * 64 + wave * 8 + sg;
      int s2048 = sbase + s_l;
      int sw = s_l & 15;
      bf16x8 x1 = *(const bf16x8_a*)&S[s_l * 128 + ((a ^ sw) * 8)];
      bf16x8 x2 = *(const bf16x8_a*)&S[s_l * 128 + (((a + 8) ^ sw) * 8)];
      u16 o1[8], o2[8];
#pragma unroll
      for (int e = 0; e < 8; ++e) {
        float j = (float)(a * 8 + e);
        float rev = (float)s2048 * __builtin_amdgcn_exp2f(-c1 * j - c2);
        rev = __builtin_amdgcn_fractf(rev);
        float sn = __builtin_amdgcn_sinf(rev);
        float cs = __builtin_amdgcn_cosf(rev);
        float v1 = (float)x1[e], v2 = (float)x2[e];
        o1[e] = f2bf(v1 * cs - v2 * sn);
        o2[e] = f2bf(v2 * cs + v1 * sn);
      }
      size_t base =
          ((((size_t)which * 2 + brow) * 16 + h) * SEQ + s2048) * HD + a * 8;
      *(uint4_a*)&qkv[base] = *(uint4*)o1;
      *(uint4_a*)&qkv[base + 64] = *(uint4*)o2;
    }
  } else {  // V: transposed copy-out, vt[b,h,d,s]
    const int d_part = tid >> 4;        // 0..31
    const int a0 = tid & 15;            // atom 0..15 (+16 for second)
#pragma unroll
    for (int pass = 0; pass < 4; ++pass) {
      int d_l = pass * 32 + d_part;     // 0..127
      int dw = d_l & 31;
      size_t rb = (((size_t)brow * 16 + h) * HD + d_l) * SEQ + sbase;
#pragma unroll
      for (int g = 0; g < 2; ++g) {
        int a2 = a0 + g * 16;
        bf16x8 y = *(const bf16x8_a*)&S[d_l * 256 + ((a2 ^ dw) * 8)];
        *(uint4_a*)&vt[rb + a2 * 8] = *(uint4_a*)&y;
      }
    }
  }
}

// ---------------- output GEMM: same core, fp32 + bias epilogue -------------
// grid (16, 16) = 256 blocks; 2 blocks/CU -> 2 rounds of 128 CUs... grid is
// 256 = 1 full round of block-slots at 2/CU every 2 CUs; scheduler packs.
__global__ __launch_bounds__(512, 4)
void gemm_out(const u16* __restrict__ A, const u16* __restrict__ Bm,
              float* __restrict__ C, const float* __restrict__ bias) {
  __shared__ __align__(16) u16 S[36864];  // 72 KiB

  const int tid = threadIdx.x;
  int hwid = blockIdx.y * 16 + blockIdx.x;
  int logical = (hwid & 7) * 32 + (hwid >> 3);
  const int bx = logical >> 4;       // 0..15 (N tile)
  const int by = logical & 15;       // 0..15 (M tile)
  const int row0 = by * 256;
  const int col0 = bx * 128;

  const u16* Ag = A + (size_t)row0 * 2048;
  const u16* Bg = Bm + (size_t)col0 * 2048;

  f32x4 acc[4][4] = {};
  mm_core<false>(Ag, Bg, S, tid, acc);

  const int lane = tid & 63;
  const int wave = tid >> 6;
  const int quad = lane >> 4;
  const int l15 = lane & 15;
  const int wm = wave >> 1;
  const int wn = wave & 1;

#pragma unroll
  for (int nt = 0; nt < 4; ++nt) {
    int d = col0 + wn * 64 + nt * 16 + l15;
    float bv = bias[d];
#pragma unroll
    for (int mt = 0; mt < 4; ++mt) {
#pragma unroll
      for (int r = 0; r < 4; ++r) {
        int row = row0 + wm * 64 + mt * 16 + quad * 4 + r;
        C[(size_t)row * DMODEL + d] = acc[mt][nt][r] + bv;
      }
    }
  }
}

// ---------------- Flash attention (R7 form: 4 waves x 32 q-rows) -----------
// grid (S/128, B*H), 256 threads; wave owns 32 Q rows (2 m-tiles).
// KV double-buffer; per tile t: compute on buf[t&1]; BARR; stage(t+2)->
// buf[t&1]; vmcnt(8) (stage(t+1) retired, stage(t+2) in flight); BARR.
// setprio(1) around both MFMA clusters. 2 blocks/CU (80 KiB LDS).
__global__ __launch_bounds__(256, 2)
void attn_kernel(const u16* __restrict__ qkv, const u16* __restrict__ vt,
                 u16* __restrict__ attn_out) {
  __shared__ __align__(16) u16 Kl[2][64 * 128];   // [kv][hd] swizzled atoms
  __shared__ __align__(16) u16 Vl[2][128 * 64];   // [d][kv] swizzled atoms
  __shared__ __align__(16) u16 Pl[4][32 * 64];    // per-wave [q][kv] swizzled

  const int tid = threadIdx.x;
  const int lane = tid & 63;
  const int wave = tid >> 6;
  const int quad = lane >> 4;
  const int l15 = lane & 15;
  const int q0 = blockIdx.x * 128;
  const int bh = blockIdx.y;
  const size_t SD = (size_t)SEQ * HD;

  const u16* Q = qkv + (size_t)bh * SD;          // which=0 (pre-scaled)
  const u16* Kg = qkv + (size_t)(32 + bh) * SD;  // which=1
  const u16* Vg = vt + (size_t)bh * SD;          // [d][s]

  // ones A-fragment in registers: row m=0 (lanes l15==0) = 1.0, else 0.
  bf16x8 onesf;
#pragma unroll
  for (int e = 0; e < 8; ++e)
    onesf[e] = (l15 == 0) ? (__bf16)1.0f : (__bf16)0.0f;

  // Q fragments first: oldest in the vmcnt FIFO, retired before first use.
  bf16x8 qf[2][4];  // Q[q=mt*16+l15][hd=c*32+quad*8+j]
#pragma unroll
  for (int mt = 0; mt < 2; ++mt) {
    int qrow = q0 + wave * 32 + mt * 16 + l15;
#pragma unroll
    for (int c = 0; c < 4; ++c)
      qf[mt][c] = *(const bf16x8*)(Q + (size_t)qrow * HD + c * 32 + quad * 8);
  }

  f32x4 of[9][2] = {};   // of[0..7]: O^T[d][q]; of[8] row0: l (ones frag)
  u16* pw = &Pl[wave][0];

  // stage one 64-wide KV tile into buffer `buf` (8 loads/thread)
  auto stage = [&](int tile, int buf) {
    int kv0 = tile * 64;
#pragma unroll
    for (int j = 0; j < 4; ++j) {
      int idx = (wave * 4 + j) * 64 + lane;
      {  // K: 64 rows x 16 atoms, swizzle ^(row&15)
        int r = idx >> 4, cs = idx & 15;
        int cc = cs ^ (r & 15);
        load_lds16(Kg + (size_t)(kv0 + r) * HD + cc * 8, &Kl[buf][idx * 8]);
      }
      {  // VT: 128 rows x 8 atoms, swizzle ^(row&7)
        int r = idx >> 3, cs = idx & 7;
        int cc = cs ^ (r & 7);
        load_lds16(Vg + (size_t)r * SEQ + kv0 + cc * 8, &Vl[buf][idx * 8]);
      }
    }
  };

  // prologue: tiles 0 and 1; vmcnt(8) = stage(0) retired (stage(1) in flight)
  stage(0, 0);
  stage(1, 1);
  VMW8;
  BARR;

#pragma unroll 2
  for (int t = 0; t < 32; ++t) {
    const u16* Kb = Kl[t & 1];
    const u16* Vb = Vl[t & 1];

    // S^T tiles: sc[nt][mt], rows kv=nt*16+quad*4+r, cols q=mt*16+l15
    f32x4 sc[4][2] = {};
    __builtin_amdgcn_s_setprio(1);
#pragma unroll
    for (int c = 0; c < 4; ++c) {
      bf16x8 kf[4];
#pragma unroll
      for (int nt = 0; nt < 4; ++nt)
        kf[nt] = *(const bf16x8*)&Kb[((nt * 16 + l15) * 16 +
                                      ((c * 4 + quad) ^ l15)) * 8];
#pragma unroll
      for (int nt = 0; nt < 4; ++nt)
#pragma unroll
        for (int mt = 0; mt < 2; ++mt)
          sc[nt][mt] = __builtin_amdgcn_mfma_f32_16x16x32_bf16(
              kf[nt], qf[mt][c], sc[nt][mt], 0, 0, 0);
    }
    __builtin_amdgcn_s_setprio(0);

    // P = exp2(sc); truncate-pack via v_perm; b64 writes (wave-private Pl)
#pragma unroll
    for (int nt = 0; nt < 4; ++nt) {
#pragma unroll
      for (int mt = 0; mt < 2; ++mt) {
        float p0 = __builtin_amdgcn_exp2f(sc[nt][mt][0]);
        float p1 = __builtin_amdgcn_exp2f(sc[nt][mt][1]);
        float p2 = __builtin_amdgcn_exp2f(sc[nt][mt][2]);
        float p3 = __builtin_amdgcn_exp2f(sc[nt][mt][3]);
        u32 lo = __builtin_amdgcn_perm(__float_as_uint(p1),
                                       __float_as_uint(p0), 0x07060302u);
        u32 hi = __builtin_amdgcn_perm(__float_as_uint(p3),
                                       __float_as_uint(p2), 0x07060302u);
        int row = mt * 16 + l15;
        int a = nt * 2 + (quad >> 1);
        int idx16 = (row * 8 + (a ^ (l15 & 7))) * 8 + (quad & 1) * 4;
        uint2 pk; pk.x = lo; pk.y = hi;
        *(uint2_a*)&pw[idx16] = pk;
      }
    }

    // O^T += V^T.P ; dt=8 uses the register ones-frag -> row sums (l)
    __builtin_amdgcn_s_setprio(1);
#pragma unroll
    for (int c = 0; c < 2; ++c) {
      bf16x8 pf[2];
#pragma unroll
      for (int mt = 0; mt < 2; ++mt)
        pf[mt] = *(const bf16x8_a*)&pw[((mt * 16 + l15) * 8 +
                                        ((c * 4 + quad) ^ (l15 & 7))) * 8];
#pragma unroll
      for (int dt = 0; dt < 9; ++dt) {
        bf16x8 vf = (dt < 8)
                        ? *(const bf16x8*)&Vb[((dt * 16 + l15) * 8 +
                                               ((c * 4 + quad) ^ (l15 & 7))) * 8]
                        : onesf;
#pragma unroll
        for (int mt = 0; mt < 2; ++mt)
          of[dt][mt] = __builtin_amdgcn_mfma_f32_16x16x32_bf16(
              vf, pf[mt], of[dt][mt], 0, 0, 0);
      }
    }
    __builtin_amdgcn_s_setprio(0);

    // all waves done reading buf[t&1]; restage it for tile t+2
    BARR;
    if (t < 30) {
      stage(t + 2, t & 1);
      VMW8;              // stage(t+1) retired; stage(t+2) stays in flight
    } else {
      VMW0;              // tail: drain (covers stage(31) at t=30)
    }
    BARR;
  }

  // l lives at of[8][mt][0] on quad-0 lanes (C row 0); broadcast by shfl.
  const int b = bh >> 4, h = bh & 15;
#pragma unroll
  for (int mt = 0; mt < 2; ++mt) {
    float lsum = __shfl(of[8][mt][0], l15, 64);
    float inv = 1.f / lsum;
    int s = q0 + wave * 32 + mt * 16 + l15;
    size_t rowb = ((size_t)b * SEQ + s) * DMODEL + h * HD;
#pragma unroll
    for (int dt = 0; dt < 8; ++dt) {
      ushort4 ov;
      ov.x = f2bf(of[dt][mt][0] * inv);
      ov.y = f2bf(of[dt][mt][1] * inv);
      ov.z = f2bf(of[dt][mt][2] * inv);
      ov.w = f2bf(of[dt][mt][3] * inv);
      *(ushort4*)&attn_out[rowb + dt * 16 + quad * 4] = ov;
    }
  }
}

extern "C" void kernel_launch(void* const* d_in, const int* in_sizes, int n_in,
                              void* d_out, int out_size, void* d_ws,
                              size_t ws_size, hipStream_t stream) {
  const float* x = (const float*)d_in[0];
  const float* Wq = (const float*)d_in[1];
  const float* Wk = (const float*)d_in[2];
  const float* Wv = (const float*)d_in[3];
  const float* Wo = (const float*)d_in[4];
  const float* bo = (const float*)d_in[5];
  float* out = (float*)d_out;

  char* ws = (char*)d_ws;
  u16* xb = (u16*)(ws);                              // 16 MiB
  u16* wqkv = (u16*)(ws + (size_t)(16 << 20));       // 24 MiB
  u16* wob = (u16*)(ws + (size_t)(40 << 20));        // 8 MiB
  u16* qkv = (u16*)(ws + (size_t)(48 << 20));        // 48 MiB: Q | K | vt
  u16* vt = qkv + (size_t)2 * 8388608;               // vt in the V slot
  u16* attn = xb;                                    // reuse after GEMMs

  // fp32 -> bf16 (one fused launch)
  conv_all<<<24576, 256, 0, stream>>>(x, Wq, Wk, Wv, Wo, xb, wqkv, wob);

  // Q,K (fused RoPE) + V^T: 256x128 tiles, 768 blocks, 2 blocks/CU
  gemm_qkv<<<dim3(48, 16), 512, 0, stream>>>(xb, wqkv, qkv, vt);
  // flash attention: 4 waves x 32 q-rows, 2 blocks/CU
  attn_kernel<<<dim3(16, 32), 256, 0, stream>>>(qkv, vt, attn);
  // out = attn @ wob^T + bo: 256x128 tiles, 256 blocks
  gemm_out<<<dim3(16, 16), 512, 0, stream>>>(attn, wob, out, bo);
}